// Round 1
// baseline (1502.873 us; speedup 1.0000x reference)
//
#include <hip/hip_runtime.h>
#include <hip/hip_bf16.h>
#include <math.h>

// Problem constants (B=2,S=2048,D=1024,H=4096,E=8,K=2)
#define NTOK 4096
#define DD   1024
#define HH   4096
#define EE   8

typedef __bf16 bf16x8 __attribute__((ext_vector_type(8)));
typedef float  f32x4  __attribute__((ext_vector_type(4)));

// ---------------- ws layout (bytes) ----------------
// [0)      counts[8]        (int)
// [64)     cursors[8]       (int)
// [128)    offsets[9]       (int)
// [256)    imp[8]           (float)
// [512)    topk_idx[N*2]    (int)    32768B
// [33280)  topk_gate[N*2]   (float)  32768B
// [66048)  slot_of[N*2]     (int)    32768B
// [98816)  token_list[N*2]  (int)    32768B
// [131584) hbuf[N*2][H]     (bf16)   67108864B
// [67240448) ybuf[N*2][D]   (float)  33554432B
// total = 100,794,880 B (~96.1 MiB)
#define WS_COUNTS     0
#define WS_CURSORS    64
#define WS_OFFSETS    128
#define WS_IMP        256
#define WS_TOPK_IDX   512
#define WS_TOPK_GATE  33280
#define WS_SLOT_OF    66048
#define WS_TOKEN_LIST 98816
#define WS_HBUF       131584
#define WS_YBUF       67240448

__device__ __forceinline__ float gelu_exact(float v) {
    return 0.5f * v * (1.0f + erff(v * 0.70710678118654752f));
}

// ---------------- Router: logits, softmax importance, top-2 ----------------
__launch_bounds__(64)
__global__ void router_kernel(const float* __restrict__ x,
                              const float* __restrict__ Wr,
                              const float* __restrict__ br,
                              int* __restrict__ counts,
                              float* __restrict__ imp,
                              int* __restrict__ topk_idx,
                              float* __restrict__ topk_gate) {
    int t = blockIdx.x;          // one wave per token
    int lane = threadIdx.x;      // 0..63
    float acc[EE];
#pragma unroll
    for (int e = 0; e < EE; e++) acc[e] = 0.0f;
    const float* xr = x + (size_t)t * DD;
    for (int d = lane; d < DD; d += 64) {
        float xv = xr[d];
        const float* w = Wr + (size_t)d * EE;
#pragma unroll
        for (int e = 0; e < EE; e++) acc[e] += xv * w[e];
    }
#pragma unroll
    for (int off = 32; off > 0; off >>= 1) {
#pragma unroll
        for (int e = 0; e < EE; e++) acc[e] += __shfl_down(acc[e], off, 64);
    }
    if (lane == 0) {
        float l[EE];
#pragma unroll
        for (int e = 0; e < EE; e++) l[e] = acc[e] + br[e];
        // full softmax -> importance accumulation
        float m = l[0];
#pragma unroll
        for (int e = 1; e < EE; e++) m = fmaxf(m, l[e]);
        float p[EE], s = 0.0f;
#pragma unroll
        for (int e = 0; e < EE; e++) { p[e] = expf(l[e] - m); s += p[e]; }
        float inv = 1.0f / s;
#pragma unroll
        for (int e = 0; e < EE; e++) atomicAdd(&imp[e], p[e] * inv);
        // top-2 (ties -> lowest index, matching jax.lax.top_k)
        int e1 = 0;
#pragma unroll
        for (int e = 1; e < EE; e++) if (l[e] > l[e1]) e1 = e;
        int e2 = -1;
#pragma unroll
        for (int e = 0; e < EE; e++) {
            if (e == e1) continue;
            if (e2 < 0 || l[e] > l[e2]) e2 = e;
        }
        float b = expf(l[e2] - l[e1]);   // <= 1, no overflow
        float g1 = 1.0f / (1.0f + b);
        float g2 = b * g1;
        topk_idx[t * 2 + 0] = e1;
        topk_idx[t * 2 + 1] = e2;
        topk_gate[t * 2 + 0] = g1;
        topk_gate[t * 2 + 1] = g2;
        atomicAdd(&counts[e1], 1);
        atomicAdd(&counts[e2], 1);
    }
}

// ---------------- Prefix offsets + aux loss ----------------
__launch_bounds__(64)
__global__ void prefix_kernel(const int* __restrict__ counts,
                              int* __restrict__ offsets,
                              int* __restrict__ cursors,
                              const float* __restrict__ imp,
                              float* __restrict__ aux_out) {
    if (threadIdx.x == 0) {
        int o = 0;
        for (int e = 0; e < EE; e++) {
            offsets[e] = o;
            cursors[e] = o;
            o += counts[e];
        }
        offsets[EE] = o;
        float aux = 0.0f;
        for (int e = 0; e < EE; e++) {
            float d = imp[e] / (float)NTOK - 1.0f / (float)EE;
            aux += d * d;
        }
        aux_out[0] = aux / (float)EE;
    }
}

// ---------------- Scatter tokens into packed per-expert slots ----------------
__launch_bounds__(256)
__global__ void scatter_kernel(const int* __restrict__ topk_idx,
                               int* __restrict__ cursors,
                               int* __restrict__ token_list,
                               int* __restrict__ slot_of) {
    int t = blockIdx.x * 256 + threadIdx.x;
    if (t >= NTOK) return;
#pragma unroll
    for (int k = 0; k < 2; k++) {
        int e = topk_idx[t * 2 + k];
        int slot = atomicAdd(&cursors[e], 1);
        token_list[slot] = t;
        slot_of[t * 2 + k] = slot;
    }
}

// ---------------- Stage 1: h = gelu(X @ W1[e] + b1[e]) ----------------
// grid (H/64, 64, E), block 256. 64x64 tile, K=1024 in steps of 32.
__launch_bounds__(256)
__global__ void ffn1_kernel(const float* __restrict__ x,
                            const float* __restrict__ W1,
                            const float* __restrict__ b1,
                            const int* __restrict__ offsets,
                            const int* __restrict__ token_list,
                            __bf16* __restrict__ hbuf) {
    int e = blockIdx.z, rt = blockIdx.y, ct = blockIdx.x;
    int obase = offsets[e];
    int cnt = offsets[e + 1] - obase;
    int rowbase = rt * 64;
    if (rowbase >= cnt) return;

    __shared__ __bf16 Xl[64][34];   // [row][k] padded
    __shared__ __bf16 Wl[32][66];   // [k][n]  padded
    __shared__ int tokl[64];

    int tid = threadIdx.x;
    if (tid < 64) {
        int r = tid;
        tokl[r] = token_list[(rowbase + r < cnt) ? (obase + rowbase + r) : obase];
    }
    __syncthreads();

    int lane = tid & 63, w = tid >> 6;
    int quad = lane >> 4, m16 = lane & 15;

    f32x4 acc[4];
#pragma unroll
    for (int i = 0; i < 4; i++) acc[i] = (f32x4){0.f, 0.f, 0.f, 0.f};

    for (int k0 = 0; k0 < DD; k0 += 32) {
        // X tile: 64 rows x 32 k (gathered, f32 -> bf16)
#pragma unroll
        for (int i = 0; i < 8; i++) {
            int idx = i * 256 + tid;
            int r = idx >> 5, kk = idx & 31;
            Xl[r][kk] = (__bf16)x[(size_t)tokl[r] * DD + k0 + kk];
        }
        // W1 tile: 32 k x 64 n (f32 -> bf16)
#pragma unroll
        for (int i = 0; i < 8; i++) {
            int idx = i * 256 + tid;
            int kk = idx >> 6, n = idx & 63;
            Wl[kk][n] = (__bf16)W1[((size_t)e * DD + k0 + kk) * HH + ct * 64 + n];
        }
        __syncthreads();

        bf16x8 a;
#pragma unroll
        for (int j = 0; j < 8; j++) a[j] = Xl[w * 16 + m16][quad * 8 + j];
#pragma unroll
        for (int t4 = 0; t4 < 4; t4++) {
            bf16x8 b;
#pragma unroll
            for (int j = 0; j < 8; j++) b[j] = Wl[quad * 8 + j][t4 * 16 + m16];
            acc[t4] = __builtin_amdgcn_mfma_f32_16x16x32_bf16(a, b, acc[t4], 0, 0, 0);
        }
        __syncthreads();
    }

    // epilogue: +b1, gelu, store bf16
#pragma unroll
    for (int t4 = 0; t4 < 4; t4++) {
        int col = ct * 64 + t4 * 16 + m16;
        float bias = b1[(size_t)e * HH + col];
#pragma unroll
        for (int r = 0; r < 4; r++) {
            int rr = w * 16 + quad * 4 + r;
            if (rowbase + rr < cnt) {
                float v = acc[t4][r] + bias;
                hbuf[(size_t)(obase + rowbase + rr) * HH + col] = (__bf16)gelu_exact(v);
            }
        }
    }
}

// ---------------- Stage 2: y = h @ W2[e] + b2[e] ----------------
// grid (D/64, 64, E), block 256. K=4096 in steps of 32.
__launch_bounds__(256)
__global__ void ffn2_kernel(const __bf16* __restrict__ hbuf,
                            const float* __restrict__ W2,
                            const float* __restrict__ b2,
                            const int* __restrict__ offsets,
                            float* __restrict__ ybuf) {
    int e = blockIdx.z, rt = blockIdx.y, ct = blockIdx.x;
    int obase = offsets[e];
    int cnt = offsets[e + 1] - obase;
    int rowbase = rt * 64;
    if (rowbase >= cnt) return;

    __shared__ __bf16 Xl[64][34];
    __shared__ __bf16 Wl[32][66];

    int tid = threadIdx.x;
    int lane = tid & 63, w = tid >> 6;
    int quad = lane >> 4, m16 = lane & 15;

    f32x4 acc[4];
#pragma unroll
    for (int i = 0; i < 4; i++) acc[i] = (f32x4){0.f, 0.f, 0.f, 0.f};

    for (int k0 = 0; k0 < HH; k0 += 32) {
        // h tile (already bf16)
#pragma unroll
        for (int i = 0; i < 8; i++) {
            int idx = i * 256 + tid;
            int r = idx >> 5, kk = idx & 31;
            int rr = rowbase + r;
            int slot = obase + ((rr < cnt) ? rr : 0);
            Xl[r][kk] = hbuf[(size_t)slot * HH + k0 + kk];
        }
        // W2 tile: 32 k x 64 n
#pragma unroll
        for (int i = 0; i < 8; i++) {
            int idx = i * 256 + tid;
            int kk = idx >> 6, n = idx & 63;
            Wl[kk][n] = (__bf16)W2[((size_t)e * HH + k0 + kk) * DD + ct * 64 + n];
        }
        __syncthreads();

        bf16x8 a;
#pragma unroll
        for (int j = 0; j < 8; j++) a[j] = Xl[w * 16 + m16][quad * 8 + j];
#pragma unroll
        for (int t4 = 0; t4 < 4; t4++) {
            bf16x8 b;
#pragma unroll
            for (int j = 0; j < 8; j++) b[j] = Wl[quad * 8 + j][t4 * 16 + m16];
            acc[t4] = __builtin_amdgcn_mfma_f32_16x16x32_bf16(a, b, acc[t4], 0, 0, 0);
        }
        __syncthreads();
    }

#pragma unroll
    for (int t4 = 0; t4 < 4; t4++) {
        int col = ct * 64 + t4 * 16 + m16;
        float bias = b2[(size_t)e * DD + col];
#pragma unroll
        for (int r = 0; r < 4; r++) {
            int rr = w * 16 + quad * 4 + r;
            if (rowbase + rr < cnt) {
                ybuf[(size_t)(obase + rowbase + rr) * DD + col] = acc[t4][r] + bias;
            }
        }
    }
}

// ---------------- Combine: out[t] = g0*y[s0] + g1*y[s1] ----------------
__launch_bounds__(256)
__global__ void combine_kernel(const float* __restrict__ ybuf,
                               const int* __restrict__ slot_of,
                               const float* __restrict__ topk_gate,
                               float* __restrict__ out) {
    int t = blockIdx.x;
    int tid = threadIdx.x;   // 256 threads, one float4 each (D=1024)
    int s0 = slot_of[t * 2 + 0], s1 = slot_of[t * 2 + 1];
    float g0 = topk_gate[t * 2 + 0], g1 = topk_gate[t * 2 + 1];
    const float4* y0 = (const float4*)(ybuf + (size_t)s0 * DD);
    const float4* y1 = (const float4*)(ybuf + (size_t)s1 * DD);
    float4 a = y0[tid], b = y1[tid];
    float4 o;
    o.x = g0 * a.x + g1 * b.x;
    o.y = g0 * a.y + g1 * b.y;
    o.z = g0 * a.z + g1 * b.z;
    o.w = g0 * a.w + g1 * b.w;
    ((float4*)(out + (size_t)t * DD))[tid] = o;
}

extern "C" void kernel_launch(void* const* d_in, const int* in_sizes, int n_in,
                              void* d_out, int out_size, void* d_ws, size_t ws_size,
                              hipStream_t stream) {
    const float* x  = (const float*)d_in[0];
    const float* Wr = (const float*)d_in[1];
    const float* br = (const float*)d_in[2];
    const float* W1 = (const float*)d_in[3];
    const float* b1 = (const float*)d_in[4];
    const float* W2 = (const float*)d_in[5];
    const float* b2 = (const float*)d_in[6];
    float* out = (float*)d_out;

    char* ws = (char*)d_ws;
    int*   counts     = (int*)(ws + WS_COUNTS);
    int*   cursors    = (int*)(ws + WS_CURSORS);
    int*   offsets    = (int*)(ws + WS_OFFSETS);
    float* imp        = (float*)(ws + WS_IMP);
    int*   topk_idx   = (int*)(ws + WS_TOPK_IDX);
    float* topk_gate  = (float*)(ws + WS_TOPK_GATE);
    int*   slot_of    = (int*)(ws + WS_SLOT_OF);
    int*   token_list = (int*)(ws + WS_TOKEN_LIST);
    __bf16* hbuf      = (__bf16*)(ws + WS_HBUF);
    float*  ybuf      = (float*)(ws + WS_YBUF);

    // zero counters + importance sums
    hipMemsetAsync(ws, 0, 512, stream);

    router_kernel<<<NTOK, 64, 0, stream>>>(x, Wr, br, counts, imp, topk_idx, topk_gate);
    prefix_kernel<<<1, 64, 0, stream>>>(counts, offsets, cursors, imp, out + (size_t)NTOK * DD);
    scatter_kernel<<<NTOK / 256, 256, 0, stream>>>(topk_idx, cursors, token_list, slot_of);

    ffn1_kernel<<<dim3(HH / 64, 64, EE), 256, 0, stream>>>(x, W1, b1, offsets, token_list, hbuf);
    ffn2_kernel<<<dim3(DD / 64, 64, EE), 256, 0, stream>>>(hbuf, W2, b2, offsets, ybuf);
    combine_kernel<<<NTOK, 256, 0, stream>>>(ybuf, slot_of, topk_gate, out);
}

// Round 2
// 1143.571 us; speedup vs baseline: 1.3142x; 1.3142x over previous
//
#include <hip/hip_runtime.h>
#include <hip/hip_bf16.h>
#include <math.h>

// Problem constants (B=2,S=2048,D=1024,H=4096,E=8,K=2)
#define NTOK 4096
#define DD   1024
#define HH   4096
#define EE   8
#define NSLOT 8192          // NTOK * K (every token picks exactly 2 experts)
#define NSLOT_PAD 8320      // +128 rows so a 128-row tile never reads OOB

typedef __bf16 bf16x8 __attribute__((ext_vector_type(8)));
typedef float  f32x4  __attribute__((ext_vector_type(4)));

// ---------------- ws layout (bytes) ----------------
#define WS_COUNTS     0
#define WS_CURSORS    64
#define WS_OFFSETS    128
#define WS_IMP        256
#define WS_TOPK_IDX   512
#define WS_TOPK_GATE  33280
#define WS_SLOT_OF    66048
#define WS_TOKEN_LIST 98816
// xg bf16 [8320][1024]         = 17,039,360 B
#define WS_XG         131584
// hbuf bf16 [8320][4096]       = 68,157,440 B
#define WS_HBUF       17170944
// ybuf f32 [8192][1024]        = 33,554,432 B
#define WS_YBUF       85328384
// W1bt bf16 [8][4096][1024]    = 67,108,864 B
#define WS_W1BT       118882816
// W2bt bf16 [8][1024][4096]    = 67,108,864 B
#define WS_W2BT       185991680
// total                        = 253,100,544 B (~241 MiB)

__device__ __forceinline__ float gelu_exact(float v) {
    return 0.5f * v * (1.0f + erff(v * 0.70710678118654752f));
}

__device__ __forceinline__ void async_copy16(const __bf16* g, __bf16* l) {
    __builtin_amdgcn_global_load_lds(
        (const __attribute__((address_space(1))) void*)g,
        (__attribute__((address_space(3))) void*)l, 16, 0, 0);
}

// ---------------- Router: logits, softmax importance, top-2 ----------------
__launch_bounds__(64)
__global__ void router_kernel(const float* __restrict__ x,
                              const float* __restrict__ Wr,
                              const float* __restrict__ br,
                              int* __restrict__ counts,
                              float* __restrict__ imp,
                              int* __restrict__ topk_idx,
                              float* __restrict__ topk_gate) {
    int t = blockIdx.x;          // one wave per token
    int lane = threadIdx.x;      // 0..63
    float acc[EE];
#pragma unroll
    for (int e = 0; e < EE; e++) acc[e] = 0.0f;
    const float* xr = x + (size_t)t * DD;
    for (int d = lane; d < DD; d += 64) {
        float xv = xr[d];
        const float* w = Wr + (size_t)d * EE;
#pragma unroll
        for (int e = 0; e < EE; e++) acc[e] += xv * w[e];
    }
#pragma unroll
    for (int off = 32; off > 0; off >>= 1) {
#pragma unroll
        for (int e = 0; e < EE; e++) acc[e] += __shfl_down(acc[e], off, 64);
    }
    if (lane == 0) {
        float l[EE];
#pragma unroll
        for (int e = 0; e < EE; e++) l[e] = acc[e] + br[e];
        float m = l[0];
#pragma unroll
        for (int e = 1; e < EE; e++) m = fmaxf(m, l[e]);
        float p[EE], s = 0.0f;
#pragma unroll
        for (int e = 0; e < EE; e++) { p[e] = expf(l[e] - m); s += p[e]; }
        float inv = 1.0f / s;
#pragma unroll
        for (int e = 0; e < EE; e++) atomicAdd(&imp[e], p[e] * inv);
        int e1 = 0;
#pragma unroll
        for (int e = 1; e < EE; e++) if (l[e] > l[e1]) e1 = e;
        int e2 = -1;
#pragma unroll
        for (int e = 0; e < EE; e++) {
            if (e == e1) continue;
            if (e2 < 0 || l[e] > l[e2]) e2 = e;
        }
        float b = expf(l[e2] - l[e1]);   // <= 1, no overflow
        float g1 = 1.0f / (1.0f + b);
        float g2 = b * g1;
        topk_idx[t * 2 + 0] = e1;
        topk_idx[t * 2 + 1] = e2;
        topk_gate[t * 2 + 0] = g1;
        topk_gate[t * 2 + 1] = g2;
        atomicAdd(&counts[e1], 1);
        atomicAdd(&counts[e2], 1);
    }
}

// ---------------- Prefix offsets + aux loss ----------------
__launch_bounds__(64)
__global__ void prefix_kernel(const int* __restrict__ counts,
                              int* __restrict__ offsets,
                              int* __restrict__ cursors,
                              const float* __restrict__ imp,
                              float* __restrict__ aux_out) {
    if (threadIdx.x == 0) {
        int o = 0;
        for (int e = 0; e < EE; e++) {
            offsets[e] = o;
            cursors[e] = o;
            o += counts[e];
        }
        offsets[EE] = o;
        float aux = 0.0f;
        for (int e = 0; e < EE; e++) {
            float d = imp[e] / (float)NTOK - 1.0f / (float)EE;
            aux += d * d;
        }
        aux_out[0] = aux / (float)EE;
    }
}

// ---------------- Scatter tokens into packed per-expert slots ----------------
__launch_bounds__(256)
__global__ void scatter_kernel(const int* __restrict__ topk_idx,
                               int* __restrict__ cursors,
                               int* __restrict__ token_list,
                               int* __restrict__ slot_of) {
    int t = blockIdx.x * 256 + threadIdx.x;
    if (t >= NTOK) return;
#pragma unroll
    for (int k = 0; k < 2; k++) {
        int e = topk_idx[t * 2 + k];
        int slot = atomicAdd(&cursors[e], 1);
        token_list[slot] = t;
        slot_of[t * 2 + k] = slot;
    }
}

// ---------------- Gather x rows into packed bf16 slot rows ----------------
__launch_bounds__(256)
__global__ void gather_x_kernel(const float* __restrict__ x,
                                const int* __restrict__ token_list,
                                __bf16* __restrict__ xg) {
    int s = blockIdx.x;
    int t = token_list[s];
    int tid = threadIdx.x;           // 256 threads x float4 = 1024 elems
    float4 v = ((const float4*)(x + (size_t)t * DD))[tid];
    __bf16 tmp[4] __attribute__((aligned(8)));
    tmp[0] = (__bf16)v.x; tmp[1] = (__bf16)v.y;
    tmp[2] = (__bf16)v.z; tmp[3] = (__bf16)v.w;
    ((ushort4*)(xg + (size_t)s * DD))[tid] = *(ushort4*)tmp;
}

// ---------------- Weight convert+transpose: [E][R][C] f32 -> [E][C][R] bf16 ----
__launch_bounds__(256)
__global__ void transpose_w_kernel(const float* __restrict__ in,
                                   __bf16* __restrict__ out,
                                   int R, int C) {
    int e = blockIdx.z;
    int c0 = blockIdx.x * 64, r0 = blockIdx.y * 64;
    __shared__ float tile[64][65];
    int tid = threadIdx.x;
    const float* ip = in + (size_t)e * R * C;
#pragma unroll
    for (int i = 0; i < 4; i++) {
        int flat = i * 256 + tid;
        int r = flat >> 4, c4 = (flat & 15) * 4;
        float4 v = *(const float4*)(ip + (size_t)(r0 + r) * C + c0 + c4);
        tile[r][c4 + 0] = v.x; tile[r][c4 + 1] = v.y;
        tile[r][c4 + 2] = v.z; tile[r][c4 + 3] = v.w;
    }
    __syncthreads();
    __bf16* op = out + (size_t)e * C * R;
#pragma unroll
    for (int i = 0; i < 4; i++) {
        int flat = i * 256 + tid;
        int c = flat >> 4, r4 = (flat & 15) * 4;
        __bf16 tmp[4] __attribute__((aligned(8)));
        tmp[0] = (__bf16)tile[r4 + 0][c];
        tmp[1] = (__bf16)tile[r4 + 1][c];
        tmp[2] = (__bf16)tile[r4 + 2][c];
        tmp[3] = (__bf16)tile[r4 + 3][c];
        *(ushort4*)(op + (size_t)(c0 + c) * R + r0 + r4) = *(ushort4*)tmp;
    }
}

// ---------------- m97-style GEMM: C[m][n] = A[m][:] . Bt[n][:] ----------------
// A: bf16 [NSLOT_PAD][K] packed slot rows; Bt: bf16 [E][N][K]; 128x128 tile,
// BK=64, 4 waves 2x2, global_load_lds width=16 staging (wave-uniform base +
// lane*16; LDS layout = unpadded [row][64] in exact staging order).
template <int N, int K, bool GELU, typename OutT>
__launch_bounds__(256)
__global__ void gemm_bt_kernel(const __bf16* __restrict__ A,
                               const __bf16* __restrict__ Bt,
                               const float* __restrict__ bias,
                               const int* __restrict__ offsets,
                               OutT* __restrict__ Out) {
    int e = blockIdx.z, ct = blockIdx.x, rt = blockIdx.y;
    int obase = offsets[e], cnt = offsets[e + 1] - obase;
    int m0 = rt * 128;
    if (m0 >= cnt) return;

    __shared__ __bf16 As[128 * 64];
    __shared__ __bf16 Bs[128 * 64];

    int tid = threadIdx.x, lane = tid & 63, wave = tid >> 6;
    int quad = lane >> 4, m16 = lane & 15;
    int wm = wave & 1, wn = wave >> 1;
    int srow = lane >> 3;            // row within 8-row chunk
    int scol = (lane & 7) * 8;       // bf16 col offset (16B per lane)

    const __bf16* Ag = A + (size_t)(obase + m0) * K;
    const __bf16* Bg = Bt + ((size_t)e * N + (size_t)ct * 128) * K;

    f32x4 acc[4][4] = {};

    for (int k0 = 0; k0 < K; k0 += 64) {
#pragma unroll
        for (int r = 0; r < 4; r++) {
            int chunk = r * 4 + wave;            // wave-uniform
            int row = chunk * 8 + srow;
            async_copy16(Ag + (size_t)row * K + k0 + scol, As + chunk * 512);
        }
#pragma unroll
        for (int r = 0; r < 4; r++) {
            int chunk = r * 4 + wave;
            int row = chunk * 8 + srow;
            async_copy16(Bg + (size_t)row * K + k0 + scol, Bs + chunk * 512);
        }
        __syncthreads();
#pragma unroll
        for (int kk = 0; kk < 64; kk += 32) {
            bf16x8 af[4], bfr[4];
#pragma unroll
            for (int mi = 0; mi < 4; mi++)
                af[mi] = *(const bf16x8*)(As + (wm * 64 + mi * 16 + m16) * 64 + kk + quad * 8);
#pragma unroll
            for (int ni = 0; ni < 4; ni++)
                bfr[ni] = *(const bf16x8*)(Bs + (wn * 64 + ni * 16 + m16) * 64 + kk + quad * 8);
#pragma unroll
            for (int mi = 0; mi < 4; mi++)
#pragma unroll
                for (int ni = 0; ni < 4; ni++)
                    acc[mi][ni] = __builtin_amdgcn_mfma_f32_16x16x32_bf16(
                        af[mi], bfr[ni], acc[mi][ni], 0, 0, 0);
        }
        __syncthreads();
    }

    // epilogue: +bias, optional gelu, store
    float bv[4];
#pragma unroll
    for (int ni = 0; ni < 4; ni++)
        bv[ni] = bias[(size_t)e * N + ct * 128 + wn * 64 + ni * 16 + m16];
#pragma unroll
    for (int mi = 0; mi < 4; mi++) {
#pragma unroll
        for (int r = 0; r < 4; r++) {
            int row = wm * 64 + mi * 16 + quad * 4 + r;
            if (m0 + row < cnt) {
                size_t orow = (size_t)(obase + m0 + row) * N + (size_t)ct * 128 + wn * 64;
#pragma unroll
                for (int ni = 0; ni < 4; ni++) {
                    float v = acc[mi][ni][r] + bv[ni];
                    if (GELU) v = gelu_exact(v);
                    Out[orow + ni * 16 + m16] = (OutT)v;
                }
            }
        }
    }
}

// ---------------- Combine: out[t] = g0*y[s0] + g1*y[s1] ----------------
__launch_bounds__(256)
__global__ void combine_kernel(const float* __restrict__ ybuf,
                               const int* __restrict__ slot_of,
                               const float* __restrict__ topk_gate,
                               float* __restrict__ out) {
    int t = blockIdx.x;
    int tid = threadIdx.x;
    int s0 = slot_of[t * 2 + 0], s1 = slot_of[t * 2 + 1];
    float g0 = topk_gate[t * 2 + 0], g1 = topk_gate[t * 2 + 1];
    const float4* y0 = (const float4*)(ybuf + (size_t)s0 * DD);
    const float4* y1 = (const float4*)(ybuf + (size_t)s1 * DD);
    float4 a = y0[tid], b = y1[tid];
    float4 o;
    o.x = g0 * a.x + g1 * b.x;
    o.y = g0 * a.y + g1 * b.y;
    o.z = g0 * a.z + g1 * b.z;
    o.w = g0 * a.w + g1 * b.w;
    ((float4*)(out + (size_t)t * DD))[tid] = o;
}

extern "C" void kernel_launch(void* const* d_in, const int* in_sizes, int n_in,
                              void* d_out, int out_size, void* d_ws, size_t ws_size,
                              hipStream_t stream) {
    const float* x  = (const float*)d_in[0];
    const float* Wr = (const float*)d_in[1];
    const float* br = (const float*)d_in[2];
    const float* W1 = (const float*)d_in[3];
    const float* b1 = (const float*)d_in[4];
    const float* W2 = (const float*)d_in[5];
    const float* b2 = (const float*)d_in[6];
    float* out = (float*)d_out;

    char* ws = (char*)d_ws;
    int*    counts     = (int*)(ws + WS_COUNTS);
    int*    cursors    = (int*)(ws + WS_CURSORS);
    int*    offsets    = (int*)(ws + WS_OFFSETS);
    float*  imp        = (float*)(ws + WS_IMP);
    int*    topk_idx   = (int*)(ws + WS_TOPK_IDX);
    float*  topk_gate  = (float*)(ws + WS_TOPK_GATE);
    int*    slot_of    = (int*)(ws + WS_SLOT_OF);
    int*    token_list = (int*)(ws + WS_TOKEN_LIST);
    __bf16* xg         = (__bf16*)(ws + WS_XG);
    __bf16* hbuf       = (__bf16*)(ws + WS_HBUF);
    float*  ybuf       = (float*)(ws + WS_YBUF);
    __bf16* W1bt       = (__bf16*)(ws + WS_W1BT);
    __bf16* W2bt       = (__bf16*)(ws + WS_W2BT);

    // zero counters + importance sums
    hipMemsetAsync(ws, 0, 512, stream);

    router_kernel<<<NTOK, 64, 0, stream>>>(x, Wr, br, counts, imp, topk_idx, topk_gate);
    prefix_kernel<<<1, 64, 0, stream>>>(counts, offsets, cursors, imp, out + (size_t)NTOK * DD);
    scatter_kernel<<<NTOK / 256, 256, 0, stream>>>(topk_idx, cursors, token_list, slot_of);
    gather_x_kernel<<<NSLOT, 256, 0, stream>>>(x, token_list, xg);

    // W1 [E][D=1024][H=4096] -> W1bt [E][H][D];  W2 [E][H=4096][D=1024] -> W2bt [E][D][H]
    transpose_w_kernel<<<dim3(HH / 64, DD / 64, EE), 256, 0, stream>>>(W1, W1bt, DD, HH);
    transpose_w_kernel<<<dim3(DD / 64, HH / 64, EE), 256, 0, stream>>>(W2, W2bt, HH, DD);

    // Stage 1: hbuf = gelu(xg @ W1 + b1)   [slots x 4096]
    gemm_bt_kernel<HH, DD, true, __bf16>
        <<<dim3(HH / 128, NSLOT / 128, EE), 256, 0, stream>>>(xg, W1bt, b1, offsets, hbuf);
    // Stage 2: ybuf = hbuf @ W2 + b2       [slots x 1024]
    gemm_bt_kernel<DD, HH, false, float>
        <<<dim3(DD / 128, NSLOT / 128, EE), 256, 0, stream>>>(hbuf, W2bt, b2, offsets, ybuf);

    combine_kernel<<<NTOK, 256, 0, stream>>>(ybuf, slot_of, topk_gate, out);
}

// Round 3
// 713.008 us; speedup vs baseline: 2.1078x; 1.6039x over previous
//
#include <hip/hip_runtime.h>
#include <hip/hip_bf16.h>
#include <math.h>

// Problem constants (B=2,S=2048,D=1024,H=4096,E=8,K=2)
#define NTOK 4096
#define DD   1024
#define HH   4096
#define EE   8
#define NSLOT 8192          // NTOK * K (every token picks exactly 2 experts)
#define NSLOT_PAD 8320      // +128 rows so a 128-row tile never reads OOB
#define RBLK 128            // router blocks (32 tokens each)

typedef __bf16 bf16x8 __attribute__((ext_vector_type(8)));
typedef float  f32x4  __attribute__((ext_vector_type(4)));

// ---------------- ws layout (bytes) ----------------
#define WS_COUNTS     0
#define WS_CURSORS    64
#define WS_OFFSETS    128
#define WS_IMP        256
#define WS_TOPK_IDX   512
#define WS_TOPK_GATE  33280
#define WS_SLOT_OF    66048
#define WS_TOKEN_LIST 98816
// xg bf16 [8320][1024]         = 17,039,360 B
#define WS_XG         131584
// hbuf bf16 [8320][4096]       = 68,157,440 B  (rows >= 8192 are guard rows)
#define WS_HBUF       17170944
// ybuf f32 [8192][1024]        = 33,554,432 B
#define WS_YBUF       85328384
// W1bt bf16 [8][4096][1024]    = 67,108,864 B
#define WS_W1BT       118882816
// W2bt bf16 [8][1024][4096]    = 67,108,864 B
#define WS_W2BT       185991680
// total                        = 253,100,544 B (~241 MiB)
// Router partials live in hbuf's guard-row region (never stored by gemm1,
// read only as masked garbage by gemm2):
#define WS_CNT_PART   (WS_HBUF + (size_t)NSLOT * HH * 2)          // int[128*8]
#define WS_IMP_PART   (WS_HBUF + (size_t)NSLOT * HH * 2 + 4096)   // float[128*8]

__device__ __forceinline__ float gelu_exact(float v) {
    return 0.5f * v * (1.0f + erff(v * 0.70710678118654752f));
}

__device__ __forceinline__ void async_copy16(const __bf16* g, __bf16* l) {
    __builtin_amdgcn_global_load_lds(
        (const __attribute__((address_space(1))) void*)g,
        (__attribute__((address_space(3))) void*)l, 16, 0, 0);
}

// ---------------- Router v2: 8 lanes per token, no global atomics ----------
__launch_bounds__(256)
__global__ void router_kernel(const float* __restrict__ x,
                              const float* __restrict__ Wr,
                              const float* __restrict__ br,
                              int* __restrict__ cntPart,
                              float* __restrict__ impPart,
                              int* __restrict__ topk_idx,
                              float* __restrict__ topk_gate) {
    __shared__ float WrL[DD * EE];      // 32 KB
    __shared__ float impW[4][EE];
    __shared__ int cntL[EE];
    int tid = threadIdx.x;
    int lane = tid & 63, wave = tid >> 6;
    int grp = lane >> 3, e = lane & 7;
    int t = blockIdx.x * 32 + wave * 8 + grp;

    for (int i = tid; i < DD * EE / 4; i += 256)
        ((float4*)WrL)[i] = ((const float4*)Wr)[i];
    if (tid < EE) cntL[tid] = 0;
    __syncthreads();

    const float* xr = x + (size_t)t * DD;
    float acc = 0.f;
#pragma unroll 4
    for (int d = 0; d < DD; d += 4) {
        float4 xv = *(const float4*)(xr + d);
        acc = fmaf(xv.x, WrL[(d + 0) * EE + e], acc);
        acc = fmaf(xv.y, WrL[(d + 1) * EE + e], acc);
        acc = fmaf(xv.z, WrL[(d + 2) * EE + e], acc);
        acc = fmaf(xv.w, WrL[(d + 3) * EE + e], acc);
    }
    float l = acc + br[e];

    // softmax prob for (t,e) across the 8 lanes of this token
    float m = l;
#pragma unroll
    for (int mk = 1; mk <= 4; mk <<= 1) m = fmaxf(m, __shfl_xor(m, mk, 64));
    float p = expf(l - m);
    float s = p;
#pragma unroll
    for (int mk = 1; mk <= 4; mk <<= 1) s += __shfl_xor(s, mk, 64);
    p /= s;

    // top-1 argmax (ties -> lowest index, matching jax.lax.top_k)
    float bl = l; int be = e;
#pragma unroll
    for (int mk = 1; mk <= 4; mk <<= 1) {
        float ol = __shfl_xor(bl, mk, 64);
        int   oe = __shfl_xor(be, mk, 64);
        if (ol > bl || (ol == bl && oe < be)) { bl = ol; be = oe; }
    }
    int e1 = be; float l1 = bl;
    // top-2
    float cl = (e == e1) ? -INFINITY : l; int ce = e;
#pragma unroll
    for (int mk = 1; mk <= 4; mk <<= 1) {
        float ol = __shfl_xor(cl, mk, 64);
        int   oe = __shfl_xor(ce, mk, 64);
        if (ol > cl || (ol == cl && oe < ce)) { cl = ol; ce = oe; }
    }
    int e2 = ce; float l2 = cl;

    if (e == 0) {
        float bb = expf(l2 - l1);        // <= 1
        float g1 = 1.f / (1.f + bb);
        topk_idx[t * 2 + 0] = e1; topk_idx[t * 2 + 1] = e2;
        topk_gate[t * 2 + 0] = g1; topk_gate[t * 2 + 1] = bb * g1;
        atomicAdd(&cntL[e1], 1);         // LDS atomics only
        atomicAdd(&cntL[e2], 1);
    }

    // importance: sum p over the 8 token-groups in this wave
#pragma unroll
    for (int mk = 8; mk <= 32; mk <<= 1) p += __shfl_xor(p, mk, 64);
    if (lane < 8) impW[wave][lane] = p;
    __syncthreads();
    if (tid < EE) {
        float v = impW[0][tid] + impW[1][tid] + impW[2][tid] + impW[3][tid];
        impPart[blockIdx.x * EE + tid] = v;
        cntPart[blockIdx.x * EE + tid] = cntL[tid];
    }
}

// ---------------- Prefix: sum partials -> offsets/cursors + aux loss -------
__launch_bounds__(64)
__global__ void prefix_kernel(const int* __restrict__ cntPart,
                              const float* __restrict__ impPart,
                              int* __restrict__ offsets,
                              int* __restrict__ cursors,
                              float* __restrict__ aux_out) {
    __shared__ int cs[EE];
    __shared__ float is[EE];
    int tid = threadIdx.x;
    if (tid < EE) {
        int c = 0; float v = 0.f;
        for (int b = 0; b < RBLK; b++) {
            c += cntPart[b * EE + tid];
            v += impPart[b * EE + tid];
        }
        cs[tid] = c; is[tid] = v;
    }
    __syncthreads();
    if (tid == 0) {
        int o = 0;
        for (int e = 0; e < EE; e++) { offsets[e] = o; cursors[e] = o; o += cs[e]; }
        offsets[EE] = o;
        float aux = 0.f;
        for (int e = 0; e < EE; e++) {
            float d = is[e] / (float)NTOK - 1.0f / (float)EE;
            aux += d * d;
        }
        aux_out[0] = aux / (float)EE;
    }
}

// ---------------- Scatter: two-phase, 8 global atomics per block -----------
__launch_bounds__(256)
__global__ void scatter_kernel(const int* __restrict__ topk_idx,
                               int* __restrict__ cursors,
                               int* __restrict__ token_list,
                               int* __restrict__ slot_of) {
    __shared__ int lcnt[EE];
    __shared__ int lbase[EE];
    int tid = threadIdx.x;
    int t = blockIdx.x * 256 + tid;
    if (tid < EE) lcnt[tid] = 0;
    __syncthreads();
    int e0 = topk_idx[t * 2 + 0], e1 = topk_idx[t * 2 + 1];
    int r0 = atomicAdd(&lcnt[e0], 1);
    int r1 = atomicAdd(&lcnt[e1], 1);
    __syncthreads();
    if (tid < EE) lbase[tid] = atomicAdd(&cursors[tid], lcnt[tid]);
    __syncthreads();
    int s0 = lbase[e0] + r0, s1 = lbase[e1] + r1;
    token_list[s0] = t; token_list[s1] = t;
    slot_of[t * 2 + 0] = s0; slot_of[t * 2 + 1] = s1;
}

// ---------------- Gather x rows into packed bf16 slot rows ----------------
__launch_bounds__(256)
__global__ void gather_x_kernel(const float* __restrict__ x,
                                const int* __restrict__ token_list,
                                __bf16* __restrict__ xg) {
    int s = blockIdx.x;
    int t = token_list[s];
    int tid = threadIdx.x;           // 256 threads x float4 = 1024 elems
    float4 v = ((const float4*)(x + (size_t)t * DD))[tid];
    __bf16 tmp[4] __attribute__((aligned(8)));
    tmp[0] = (__bf16)v.x; tmp[1] = (__bf16)v.y;
    tmp[2] = (__bf16)v.z; tmp[3] = (__bf16)v.w;
    ((ushort4*)(xg + (size_t)s * DD))[tid] = *(ushort4*)tmp;
}

// ---------------- Weight convert+transpose: [E][R][C] f32 -> [E][C][R] bf16 ----
__launch_bounds__(256)
__global__ void transpose_w_kernel(const float* __restrict__ in,
                                   __bf16* __restrict__ out,
                                   int R, int C) {
    int e = blockIdx.z;
    int c0 = blockIdx.x * 64, r0 = blockIdx.y * 64;
    __shared__ float tile[64][65];
    int tid = threadIdx.x;
    const float* ip = in + (size_t)e * R * C;
#pragma unroll
    for (int i = 0; i < 4; i++) {
        int flat = i * 256 + tid;
        int r = flat >> 4, c4 = (flat & 15) * 4;
        float4 v = *(const float4*)(ip + (size_t)(r0 + r) * C + c0 + c4);
        tile[r][c4 + 0] = v.x; tile[r][c4 + 1] = v.y;
        tile[r][c4 + 2] = v.z; tile[r][c4 + 3] = v.w;
    }
    __syncthreads();
    __bf16* op = out + (size_t)e * C * R;
#pragma unroll
    for (int i = 0; i < 4; i++) {
        int flat = i * 256 + tid;
        int c = flat >> 4, r4 = (flat & 15) * 4;
        __bf16 tmp[4] __attribute__((aligned(8)));
        tmp[0] = (__bf16)tile[r4 + 0][c];
        tmp[1] = (__bf16)tile[r4 + 1][c];
        tmp[2] = (__bf16)tile[r4 + 2][c];
        tmp[3] = (__bf16)tile[r4 + 3][c];
        *(ushort4*)(op + (size_t)(c0 + c) * R + r0 + r4) = *(ushort4*)tmp;
    }
}

// ---------------- m97-style GEMM: C[m][n] = A[m][:] . Bt[n][:] ----------------
template <int N, int K, bool GELU, typename OutT>
__launch_bounds__(256)
__global__ void gemm_bt_kernel(const __bf16* __restrict__ A,
                               const __bf16* __restrict__ Bt,
                               const float* __restrict__ bias,
                               const int* __restrict__ offsets,
                               OutT* __restrict__ Out) {
    int e = blockIdx.z, ct = blockIdx.x, rt = blockIdx.y;
    int obase = offsets[e], cnt = offsets[e + 1] - obase;
    int m0 = rt * 128;
    if (m0 >= cnt) return;

    __shared__ __bf16 As[128 * 64];
    __shared__ __bf16 Bs[128 * 64];

    int tid = threadIdx.x, lane = tid & 63, wave = tid >> 6;
    int quad = lane >> 4, m16 = lane & 15;
    int wm = wave & 1, wn = wave >> 1;
    int srow = lane >> 3;            // row within 8-row chunk
    int scol = (lane & 7) * 8;       // bf16 col offset (16B per lane)

    const __bf16* Ag = A + (size_t)(obase + m0) * K;
    const __bf16* Bg = Bt + ((size_t)e * N + (size_t)ct * 128) * K;

    f32x4 acc[4][4] = {};

    for (int k0 = 0; k0 < K; k0 += 64) {
#pragma unroll
        for (int r = 0; r < 4; r++) {
            int chunk = r * 4 + wave;            // wave-uniform
            int row = chunk * 8 + srow;
            async_copy16(Ag + (size_t)row * K + k0 + scol, As + chunk * 512);
        }
#pragma unroll
        for (int r = 0; r < 4; r++) {
            int chunk = r * 4 + wave;
            int row = chunk * 8 + srow;
            async_copy16(Bg + (size_t)row * K + k0 + scol, Bs + chunk * 512);
        }
        __syncthreads();
#pragma unroll
        for (int kk = 0; kk < 64; kk += 32) {
            bf16x8 af[4], bfr[4];
#pragma unroll
            for (int mi = 0; mi < 4; mi++)
                af[mi] = *(const bf16x8*)(As + (wm * 64 + mi * 16 + m16) * 64 + kk + quad * 8);
#pragma unroll
            for (int ni = 0; ni < 4; ni++)
                bfr[ni] = *(const bf16x8*)(Bs + (wn * 64 + ni * 16 + m16) * 64 + kk + quad * 8);
#pragma unroll
            for (int mi = 0; mi < 4; mi++)
#pragma unroll
                for (int ni = 0; ni < 4; ni++)
                    acc[mi][ni] = __builtin_amdgcn_mfma_f32_16x16x32_bf16(
                        af[mi], bfr[ni], acc[mi][ni], 0, 0, 0);
        }
        __syncthreads();
    }

    // epilogue: +bias, optional gelu, store
    float bv[4];
#pragma unroll
    for (int ni = 0; ni < 4; ni++)
        bv[ni] = bias[(size_t)e * N + ct * 128 + wn * 64 + ni * 16 + m16];
#pragma unroll
    for (int mi = 0; mi < 4; mi++) {
#pragma unroll
        for (int r = 0; r < 4; r++) {
            int row = wm * 64 + mi * 16 + quad * 4 + r;
            if (m0 + row < cnt) {
                size_t orow = (size_t)(obase + m0 + row) * N + (size_t)ct * 128 + wn * 64;
#pragma unroll
                for (int ni = 0; ni < 4; ni++) {
                    float v = acc[mi][ni][r] + bv[ni];
                    if (GELU) v = gelu_exact(v);
                    Out[orow + ni * 16 + m16] = (OutT)v;
                }
            }
        }
    }
}

// ---------------- Combine: out[t] = g0*y[s0] + g1*y[s1] ----------------
__launch_bounds__(256)
__global__ void combine_kernel(const float* __restrict__ ybuf,
                               const int* __restrict__ slot_of,
                               const float* __restrict__ topk_gate,
                               float* __restrict__ out) {
    int t = blockIdx.x;
    int tid = threadIdx.x;
    int s0 = slot_of[t * 2 + 0], s1 = slot_of[t * 2 + 1];
    float g0 = topk_gate[t * 2 + 0], g1 = topk_gate[t * 2 + 1];
    const float4* y0 = (const float4*)(ybuf + (size_t)s0 * DD);
    const float4* y1 = (const float4*)(ybuf + (size_t)s1 * DD);
    float4 a = y0[tid], b = y1[tid];
    float4 o;
    o.x = g0 * a.x + g1 * b.x;
    o.y = g0 * a.y + g1 * b.y;
    o.z = g0 * a.z + g1 * b.z;
    o.w = g0 * a.w + g1 * b.w;
    ((float4*)(out + (size_t)t * DD))[tid] = o;
}

extern "C" void kernel_launch(void* const* d_in, const int* in_sizes, int n_in,
                              void* d_out, int out_size, void* d_ws, size_t ws_size,
                              hipStream_t stream) {
    const float* x  = (const float*)d_in[0];
    const float* Wr = (const float*)d_in[1];
    const float* br = (const float*)d_in[2];
    const float* W1 = (const float*)d_in[3];
    const float* b1 = (const float*)d_in[4];
    const float* W2 = (const float*)d_in[5];
    const float* b2 = (const float*)d_in[6];
    float* out = (float*)d_out;

    char* ws = (char*)d_ws;
    int*    offsets    = (int*)(ws + WS_OFFSETS);
    int*    cursors    = (int*)(ws + WS_CURSORS);
    int*    topk_idx   = (int*)(ws + WS_TOPK_IDX);
    float*  topk_gate  = (float*)(ws + WS_TOPK_GATE);
    int*    slot_of    = (int*)(ws + WS_SLOT_OF);
    int*    token_list = (int*)(ws + WS_TOKEN_LIST);
    __bf16* xg         = (__bf16*)(ws + WS_XG);
    __bf16* hbuf       = (__bf16*)(ws + WS_HBUF);
    float*  ybuf       = (float*)(ws + WS_YBUF);
    __bf16* W1bt       = (__bf16*)(ws + WS_W1BT);
    __bf16* W2bt       = (__bf16*)(ws + WS_W2BT);
    int*    cntPart    = (int*)(ws + WS_CNT_PART);
    float*  impPart    = (float*)(ws + WS_IMP_PART);

    router_kernel<<<RBLK, 256, 0, stream>>>(x, Wr, br, cntPart, impPart, topk_idx, topk_gate);
    prefix_kernel<<<1, 64, 0, stream>>>(cntPart, impPart, offsets, cursors, out + (size_t)NTOK * DD);
    scatter_kernel<<<NTOK / 256, 256, 0, stream>>>(topk_idx, cursors, token_list, slot_of);
    gather_x_kernel<<<NSLOT, 256, 0, stream>>>(x, token_list, xg);

    // W1 [E][D=1024][H=4096] -> W1bt [E][H][D];  W2 [E][H=4096][D=1024] -> W2bt [E][D][H]
    transpose_w_kernel<<<dim3(HH / 64, DD / 64, EE), 256, 0, stream>>>(W1, W1bt, DD, HH);
    transpose_w_kernel<<<dim3(DD / 64, HH / 64, EE), 256, 0, stream>>>(W2, W2bt, HH, DD);

    // Stage 1: hbuf = gelu(xg @ W1 + b1)   [slots x 4096]
    gemm_bt_kernel<HH, DD, true, __bf16>
        <<<dim3(HH / 128, NSLOT / 128, EE), 256, 0, stream>>>(xg, W1bt, b1, offsets, hbuf);
    // Stage 2: ybuf = hbuf @ W2 + b2       [slots x 1024]
    gemm_bt_kernel<DD, HH, false, float>
        <<<dim3(DD / 128, NSLOT / 128, EE), 256, 0, stream>>>(hbuf, W2bt, b2, offsets, ybuf);

    combine_kernel<<<NTOK, 256, 0, stream>>>(ybuf, slot_of, topk_gate, out);
}

// Round 4
// 656.579 us; speedup vs baseline: 2.2889x; 1.0859x over previous
//
#include <hip/hip_runtime.h>
#include <hip/hip_bf16.h>
#include <math.h>

// Problem constants (B=2,S=2048,D=1024,H=4096,E=8,K=2)
#define NTOK 4096
#define DD   1024
#define HH   4096
#define EE   8
#define NSLOT 8192          // NTOK * K (every token picks exactly 2 experts)
#define NSLOT_PAD 8320      // +128 rows so a 128-row tile never reads OOB
#define RBLK 128            // router blocks (32 tokens each)

typedef __bf16 bf16x8 __attribute__((ext_vector_type(8)));
typedef float  f32x4  __attribute__((ext_vector_type(4)));
typedef unsigned short u16x8 __attribute__((ext_vector_type(8)));

// s_waitcnt imm encoding (gfx9 family): vmcnt[3:0]+[15:14], expcnt[6:4], lgkmcnt[11:8]
#define WAITCNT_VM(n) (((n) & 0xF) | (0x7 << 4) | (0xF << 8) | (((n) >> 4) << 14))

// ---------------- ws layout (bytes) ----------------
#define WS_COUNTS     0
#define WS_CURSORS    64
#define WS_OFFSETS    128
#define WS_IMP        256
#define WS_TOPK_IDX   512
#define WS_TOPK_GATE  33280
#define WS_SLOT_OF    66048
#define WS_TOKEN_LIST 98816
// xg bf16 [8320][1024]         = 17,039,360 B
#define WS_XG         131584
// hbuf bf16 [8320][4096]       = 68,157,440 B  (rows >= 8192 are guard rows)
#define WS_HBUF       17170944
// ybuf f32 [8192][1024]        = 33,554,432 B
#define WS_YBUF       85328384
// W1bt bf16 [8][4096][1024]    = 67,108,864 B
#define WS_W1BT       118882816
// W2bt bf16 [8][1024][4096]    = 67,108,864 B
#define WS_W2BT       185991680
// total                        = 253,100,544 B (~241 MiB)
// Router partials live in hbuf's guard-row region (finite poison, never stored
// by gemm1, read only as masked garbage by gemm2):
#define WS_CNT_PART   (WS_HBUF + (size_t)NSLOT * HH * 2)          // int[128*8]
#define WS_IMP_PART   (WS_HBUF + (size_t)NSLOT * HH * 2 + 4096)   // float[128*8]

__device__ __forceinline__ float gelu_exact(float v) {
    return 0.5f * v * (1.0f + erff(v * 0.70710678118654752f));
}

__device__ __forceinline__ void async_copy16(const __bf16* g, __bf16* l) {
    __builtin_amdgcn_global_load_lds(
        (const __attribute__((address_space(1))) void*)g,
        (__attribute__((address_space(3))) void*)l, 16, 0, 0);
}

// ---------------- Router: 8 lanes per token, no global atomics ----------
__launch_bounds__(256)
__global__ void router_kernel(const float* __restrict__ x,
                              const float* __restrict__ Wr,
                              const float* __restrict__ br,
                              int* __restrict__ cntPart,
                              float* __restrict__ impPart,
                              int* __restrict__ topk_idx,
                              float* __restrict__ topk_gate) {
    __shared__ float WrL[DD * EE];      // 32 KB
    __shared__ float impW[4][EE];
    __shared__ int cntL[EE];
    int tid = threadIdx.x;
    int lane = tid & 63, wave = tid >> 6;
    int grp = lane >> 3, e = lane & 7;
    int t = blockIdx.x * 32 + wave * 8 + grp;

    for (int i = tid; i < DD * EE / 4; i += 256)
        ((float4*)WrL)[i] = ((const float4*)Wr)[i];
    if (tid < EE) cntL[tid] = 0;
    __syncthreads();

    const float* xr = x + (size_t)t * DD;
    float acc = 0.f;
#pragma unroll 4
    for (int d = 0; d < DD; d += 4) {
        float4 xv = *(const float4*)(xr + d);
        acc = fmaf(xv.x, WrL[(d + 0) * EE + e], acc);
        acc = fmaf(xv.y, WrL[(d + 1) * EE + e], acc);
        acc = fmaf(xv.z, WrL[(d + 2) * EE + e], acc);
        acc = fmaf(xv.w, WrL[(d + 3) * EE + e], acc);
    }
    float l = acc + br[e];

    // softmax prob for (t,e) across the 8 lanes of this token
    float m = l;
#pragma unroll
    for (int mk = 1; mk <= 4; mk <<= 1) m = fmaxf(m, __shfl_xor(m, mk, 64));
    float p = expf(l - m);
    float s = p;
#pragma unroll
    for (int mk = 1; mk <= 4; mk <<= 1) s += __shfl_xor(s, mk, 64);
    p /= s;

    // top-1 argmax (ties -> lowest index, matching jax.lax.top_k)
    float bl = l; int be = e;
#pragma unroll
    for (int mk = 1; mk <= 4; mk <<= 1) {
        float ol = __shfl_xor(bl, mk, 64);
        int   oe = __shfl_xor(be, mk, 64);
        if (ol > bl || (ol == bl && oe < be)) { bl = ol; be = oe; }
    }
    int e1 = be; float l1 = bl;
    // top-2
    float cl = (e == e1) ? -INFINITY : l; int ce = e;
#pragma unroll
    for (int mk = 1; mk <= 4; mk <<= 1) {
        float ol = __shfl_xor(cl, mk, 64);
        int   oe = __shfl_xor(ce, mk, 64);
        if (ol > cl || (ol == cl && oe < ce)) { cl = ol; ce = oe; }
    }
    int e2 = ce; float l2 = cl;

    if (e == 0) {
        float bb = expf(l2 - l1);        // <= 1
        float g1 = 1.f / (1.f + bb);
        topk_idx[t * 2 + 0] = e1; topk_idx[t * 2 + 1] = e2;
        topk_gate[t * 2 + 0] = g1; topk_gate[t * 2 + 1] = bb * g1;
        atomicAdd(&cntL[e1], 1);         // LDS atomics only
        atomicAdd(&cntL[e2], 1);
    }

    // importance: sum p over the 8 token-groups in this wave
#pragma unroll
    for (int mk = 8; mk <= 32; mk <<= 1) p += __shfl_xor(p, mk, 64);
    if (lane < 8) impW[wave][lane] = p;
    __syncthreads();
    if (tid < EE) {
        float v = impW[0][tid] + impW[1][tid] + impW[2][tid] + impW[3][tid];
        impPart[blockIdx.x * EE + tid] = v;
        cntPart[blockIdx.x * EE + tid] = cntL[tid];
    }
}

// ---------------- Prefix: sum partials -> offsets/cursors + aux loss -------
__launch_bounds__(64)
__global__ void prefix_kernel(const int* __restrict__ cntPart,
                              const float* __restrict__ impPart,
                              int* __restrict__ offsets,
                              int* __restrict__ cursors,
                              float* __restrict__ aux_out) {
    __shared__ int cs[EE];
    __shared__ float is[EE];
    int tid = threadIdx.x;
    if (tid < EE) {
        int c = 0; float v = 0.f;
        for (int b = 0; b < RBLK; b++) {
            c += cntPart[b * EE + tid];
            v += impPart[b * EE + tid];
        }
        cs[tid] = c; is[tid] = v;
    }
    __syncthreads();
    if (tid == 0) {
        int o = 0;
        for (int e = 0; e < EE; e++) { offsets[e] = o; cursors[e] = o; o += cs[e]; }
        offsets[EE] = o;
        float aux = 0.f;
        for (int e = 0; e < EE; e++) {
            float d = is[e] / (float)NTOK - 1.0f / (float)EE;
            aux += d * d;
        }
        aux_out[0] = aux / (float)EE;
    }
}

// ---------------- Scatter: two-phase, 8 global atomics per block -----------
__launch_bounds__(256)
__global__ void scatter_kernel(const int* __restrict__ topk_idx,
                               int* __restrict__ cursors,
                               int* __restrict__ token_list,
                               int* __restrict__ slot_of) {
    __shared__ int lcnt[EE];
    __shared__ int lbase[EE];
    int tid = threadIdx.x;
    int t = blockIdx.x * 256 + tid;
    if (tid < EE) lcnt[tid] = 0;
    __syncthreads();
    int e0 = topk_idx[t * 2 + 0], e1 = topk_idx[t * 2 + 1];
    int r0 = atomicAdd(&lcnt[e0], 1);
    int r1 = atomicAdd(&lcnt[e1], 1);
    __syncthreads();
    if (tid < EE) lbase[tid] = atomicAdd(&cursors[tid], lcnt[tid]);
    __syncthreads();
    int s0 = lbase[e0] + r0, s1 = lbase[e1] + r1;
    token_list[s0] = t; token_list[s1] = t;
    slot_of[t * 2 + 0] = s0; slot_of[t * 2 + 1] = s1;
}

// ---------------- Gather x rows into packed bf16 slot rows ----------------
__launch_bounds__(256)
__global__ void gather_x_kernel(const float* __restrict__ x,
                                const int* __restrict__ token_list,
                                __bf16* __restrict__ xg) {
    int s = blockIdx.x;
    int t = token_list[s];
    int tid = threadIdx.x;           // 256 threads x float4 = 1024 elems
    float4 v = ((const float4*)(x + (size_t)t * DD))[tid];
    __bf16 tmp[4] __attribute__((aligned(8)));
    tmp[0] = (__bf16)v.x; tmp[1] = (__bf16)v.y;
    tmp[2] = (__bf16)v.z; tmp[3] = (__bf16)v.w;
    ((ushort4*)(xg + (size_t)s * DD))[tid] = *(ushort4*)tmp;
}

// ---------------- Weight convert+transpose: [E][R][C] f32 -> [E][C][R] bf16 ----
__launch_bounds__(256)
__global__ void transpose_w_kernel(const float* __restrict__ in,
                                   __bf16* __restrict__ out,
                                   int R, int C) {
    int e = blockIdx.z;
    int c0 = blockIdx.x * 64, r0 = blockIdx.y * 64;
    __shared__ float tile[64][65];
    int tid = threadIdx.x;
    const float* ip = in + (size_t)e * R * C;
#pragma unroll
    for (int i = 0; i < 4; i++) {
        int flat = i * 256 + tid;
        int r = flat >> 4, c4 = (flat & 15) * 4;
        float4 v = *(const float4*)(ip + (size_t)(r0 + r) * C + c0 + c4);
        tile[r][c4 + 0] = v.x; tile[r][c4 + 1] = v.y;
        tile[r][c4 + 2] = v.z; tile[r][c4 + 3] = v.w;
    }
    __syncthreads();
    __bf16* op = out + (size_t)e * C * R;
    // write side: 16B per lane (ushort8), 2 passes
#pragma unroll
    for (int i = 0; i < 2; i++) {
        int flat = i * 256 + tid;
        int c = flat >> 3, r8 = (flat & 7) * 8;
        __bf16 tmp[8] __attribute__((aligned(16)));
#pragma unroll
        for (int j = 0; j < 8; j++) tmp[j] = (__bf16)tile[r8 + j][c];
        *(u16x8*)(op + (size_t)(c0 + c) * R + r0 + r8) = *(u16x8*)tmp;
    }
}

// ---------------- GEMM: C[m][n] = A[m][:] . Bt[n][:]  (dbuf + swizzle) -----
// A: bf16 [NSLOT_PAD][K] packed slot rows; Bt: bf16 [E][N][K]; 128x128 tile,
// BK=64, 4 waves 2x2. Staging via global_load_lds width=16 (wave-uniform base
// + lane*16). XOR chunk swizzle: lane loads global col-chunk (lane&7)^(srow),
// fragment reads chunk ((kk/8+quad)^(row&7)). Explicit 2-deep LDS double
// buffer with raw s_barrier + s_waitcnt vmcnt(8) (never 0 mid-loop).
template <int N, int K, bool GELU, typename OutT>
__launch_bounds__(256, 2)
__global__ void gemm_bt_kernel(const __bf16* __restrict__ A,
                               const __bf16* __restrict__ Bt,
                               const float* __restrict__ bias,
                               const int* __restrict__ offsets,
                               OutT* __restrict__ Out) {
    int e = blockIdx.z, ct = blockIdx.x, rt = blockIdx.y;
    int obase = offsets[e], cnt = offsets[e + 1] - obase;
    int m0 = rt * 128;
    if (m0 >= cnt) return;

    __shared__ __bf16 As[2][128 * 64];
    __shared__ __bf16 Bs[2][128 * 64];

    int tid = threadIdx.x, lane = tid & 63, wave = tid >> 6;
    int quad = lane >> 4, m16 = lane & 15;
    int wm = wave & 1, wn = wave >> 1;
    int srow = lane >> 3;                        // row within 8-row chunk (0..7)
    int scol = ((lane & 7) ^ srow) * 8;          // swizzled bf16 col offset
    int swz = m16 & 7;                           // fragment-read swizzle key

    const __bf16* Ag = A + (size_t)(obase + m0) * K;
    const __bf16* Bg = Bt + ((size_t)e * N + (size_t)ct * 128) * K;

    f32x4 acc[4][4] = {};

#define STAGE(buf, k0)                                                        \
    {                                                                         \
        _Pragma("unroll")                                                     \
        for (int r = 0; r < 4; r++) {                                         \
            int chunk = r * 4 + wave; /* wave-uniform */                      \
            int row = chunk * 8 + srow;                                       \
            async_copy16(Ag + (size_t)row * K + (k0) + scol, As[buf] + chunk * 512); \
        }                                                                     \
        _Pragma("unroll")                                                     \
        for (int r = 0; r < 4; r++) {                                         \
            int chunk = r * 4 + wave;                                         \
            int row = chunk * 8 + srow;                                       \
            async_copy16(Bg + (size_t)row * K + (k0) + scol, Bs[buf] + chunk * 512); \
        }                                                                     \
    }

#define COMPUTE(buf)                                                          \
    {                                                                         \
        const __bf16* Ac = As[buf];                                           \
        const __bf16* Bc = Bs[buf];                                           \
        _Pragma("unroll")                                                     \
        for (int kk = 0; kk < 64; kk += 32) {                                 \
            int kkc = kk >> 3;                                                \
            bf16x8 af[4], bfr[4];                                             \
            _Pragma("unroll")                                                 \
            for (int mi = 0; mi < 4; mi++)                                    \
                af[mi] = *(const bf16x8*)(Ac + (wm * 64 + mi * 16 + m16) * 64 \
                                          + (((kkc + quad) ^ swz) * 8));      \
            _Pragma("unroll")                                                 \
            for (int ni = 0; ni < 4; ni++)                                    \
                bfr[ni] = *(const bf16x8*)(Bc + (wn * 64 + ni * 16 + m16) * 64\
                                           + (((kkc + quad) ^ swz) * 8));     \
            _Pragma("unroll")                                                 \
            for (int mi = 0; mi < 4; mi++)                                    \
                _Pragma("unroll")                                             \
                for (int ni = 0; ni < 4; ni++)                                \
                    acc[mi][ni] = __builtin_amdgcn_mfma_f32_16x16x32_bf16(    \
                        af[mi], bfr[ni], acc[mi][ni], 0, 0, 0);               \
        }                                                                     \
    }

    STAGE(0, 0);
    int cur = 0;
    for (int k0 = 64; k0 < K; k0 += 64) {
        STAGE(cur ^ 1, k0);                          // prefetch next tile
        __builtin_amdgcn_s_waitcnt(WAITCNT_VM(8));   // cur tile's 8 loads done
        __builtin_amdgcn_s_barrier();
        COMPUTE(cur);
        __builtin_amdgcn_s_barrier();                // protect cur buf reuse
        cur ^= 1;
    }
    __builtin_amdgcn_s_waitcnt(WAITCNT_VM(0));
    __builtin_amdgcn_s_barrier();
    COMPUTE(cur);
#undef STAGE
#undef COMPUTE

    // epilogue: +bias, optional gelu, store
    float bv[4];
#pragma unroll
    for (int ni = 0; ni < 4; ni++)
        bv[ni] = bias[(size_t)e * N + ct * 128 + wn * 64 + ni * 16 + m16];
#pragma unroll
    for (int mi = 0; mi < 4; mi++) {
#pragma unroll
        for (int r = 0; r < 4; r++) {
            int row = wm * 64 + mi * 16 + quad * 4 + r;
            if (m0 + row < cnt) {
                size_t orow = (size_t)(obase + m0 + row) * N + (size_t)ct * 128 + wn * 64;
#pragma unroll
                for (int ni = 0; ni < 4; ni++) {
                    float v = acc[mi][ni][r] + bv[ni];
                    if (GELU) v = gelu_exact(v);
                    Out[orow + ni * 16 + m16] = (OutT)v;
                }
            }
        }
    }
}

// ---------------- Combine: out[t] = g0*y[s0] + g1*y[s1] ----------------
__launch_bounds__(256)
__global__ void combine_kernel(const float* __restrict__ ybuf,
                               const int* __restrict__ slot_of,
                               const float* __restrict__ topk_gate,
                               float* __restrict__ out) {
    int t = blockIdx.x;
    int tid = threadIdx.x;
    int s0 = slot_of[t * 2 + 0], s1 = slot_of[t * 2 + 1];
    float g0 = topk_gate[t * 2 + 0], g1 = topk_gate[t * 2 + 1];
    const float4* y0 = (const float4*)(ybuf + (size_t)s0 * DD);
    const float4* y1 = (const float4*)(ybuf + (size_t)s1 * DD);
    float4 a = y0[tid], b = y1[tid];
    float4 o;
    o.x = g0 * a.x + g1 * b.x;
    o.y = g0 * a.y + g1 * b.y;
    o.z = g0 * a.z + g1 * b.z;
    o.w = g0 * a.w + g1 * b.w;
    ((float4*)(out + (size_t)t * DD))[tid] = o;
}

extern "C" void kernel_launch(void* const* d_in, const int* in_sizes, int n_in,
                              void* d_out, int out_size, void* d_ws, size_t ws_size,
                              hipStream_t stream) {
    const float* x  = (const float*)d_in[0];
    const float* Wr = (const float*)d_in[1];
    const float* br = (const float*)d_in[2];
    const float* W1 = (const float*)d_in[3];
    const float* b1 = (const float*)d_in[4];
    const float* W2 = (const float*)d_in[5];
    const float* b2 = (const float*)d_in[6];
    float* out = (float*)d_out;

    char* ws = (char*)d_ws;
    int*    offsets    = (int*)(ws + WS_OFFSETS);
    int*    cursors    = (int*)(ws + WS_CURSORS);
    int*    topk_idx   = (int*)(ws + WS_TOPK_IDX);
    float*  topk_gate  = (float*)(ws + WS_TOPK_GATE);
    int*    slot_of    = (int*)(ws + WS_SLOT_OF);
    int*    token_list = (int*)(ws + WS_TOKEN_LIST);
    __bf16* xg         = (__bf16*)(ws + WS_XG);
    __bf16* hbuf       = (__bf16*)(ws + WS_HBUF);
    float*  ybuf       = (float*)(ws + WS_YBUF);
    __bf16* W1bt       = (__bf16*)(ws + WS_W1BT);
    __bf16* W2bt       = (__bf16*)(ws + WS_W2BT);
    int*    cntPart    = (int*)(ws + WS_CNT_PART);
    float*  impPart    = (float*)(ws + WS_IMP_PART);

    router_kernel<<<RBLK, 256, 0, stream>>>(x, Wr, br, cntPart, impPart, topk_idx, topk_gate);
    prefix_kernel<<<1, 64, 0, stream>>>(cntPart, impPart, offsets, cursors, out + (size_t)NTOK * DD);
    scatter_kernel<<<NTOK / 256, 256, 0, stream>>>(topk_idx, cursors, token_list, slot_of);
    gather_x_kernel<<<NSLOT, 256, 0, stream>>>(x, token_list, xg);

    // W1 [E][D=1024][H=4096] -> W1bt [E][H][D];  W2 [E][H=4096][D=1024] -> W2bt [E][D][H]
    transpose_w_kernel<<<dim3(HH / 64, DD / 64, EE), 256, 0, stream>>>(W1, W1bt, DD, HH);
    transpose_w_kernel<<<dim3(DD / 64, HH / 64, EE), 256, 0, stream>>>(W2, W2bt, HH, DD);

    // Stage 1: hbuf = gelu(xg @ W1 + b1)   [slots x 4096]
    gemm_bt_kernel<HH, DD, true, __bf16>
        <<<dim3(HH / 128, NSLOT / 128, EE), 256, 0, stream>>>(xg, W1bt, b1, offsets, hbuf);
    // Stage 2: ybuf = hbuf @ W2 + b2       [slots x 1024]
    gemm_bt_kernel<DD, HH, false, float>
        <<<dim3(DD / 128, NSLOT / 128, EE), 256, 0, stream>>>(hbuf, W2bt, b2, offsets, ybuf);

    combine_kernel<<<NTOK, 256, 0, stream>>>(ybuf, slot_of, topk_gate, out);
}